// Round 11
// baseline (269.719 us; speedup 1.0000x reference)
//
#include <hip/hip_runtime.h>
#include <hip/hip_bf16.h>

// Problem constants
#define NB 32
#define T_LEN 8192
#define CKC 256
#define UQ 128
#define NSEG 8               // T-segments per n
#define SEG_ROWS 1024        // T_LEN / NSEG
#define WAVE_ROWS 128        // SEG_ROWS / 8 waves
#define NTILES 8             // WAVE_ROWS / 16
#define PART_STRIDE 258
#define FIXED_MAX 25.0f      // scores provably < 25; exp(st-25) in [e^-60, e^-2]

typedef short short8 __attribute__((ext_vector_type(8)));
typedef float f32x4 __attribute__((ext_vector_type(4)));
typedef unsigned short ushort4_t __attribute__((ext_vector_type(4)));

__device__ __forceinline__ unsigned short f2bf(float x) {
  union { float f; unsigned u; } un; un.f = x;
  unsigned r = un.u + 0x7FFFu + ((un.u >> 16) & 1u);
  return (unsigned short)(r >> 16);
}
__device__ __forceinline__ float bf2f(unsigned short h) {
  union { unsigned u; float f; } un; un.u = ((unsigned)h) << 16;
  return un.f;
}
__device__ __forceinline__ float fast_tanh(float x) {
  float e = __expf(2.0f * x);
  return 1.0f - 2.0f / (e + 1.0f);   // saturates correctly for |x| large
}
__device__ __forceinline__ ushort4_t pack_bf16x4(f32x4 x) {
  union { __hip_bfloat162 h; unsigned short u[2]; } a, b;
  a.h = __float22bfloat162_rn(make_float2(x[0], x[1]));
  b.h = __float22bfloat162_rn(make_float2(x[2], x[3]));
  ushort4_t r; r[0] = a.u[0]; r[1] = a.u[1]; r[2] = b.u[0]; r[3] = b.u[1];
  return r;
}
// Publishing barrier: waits only this wave's LDS ops, does NOT drain vmcnt.
__device__ __forceinline__ void barrier_lgkm() {
  asm volatile("s_waitcnt lgkmcnt(0)" ::: "memory");
  __builtin_amdgcn_s_barrier();
}
// Pure-VALU 16-lane reduction step (DPP row_shl, 0-fill): after N=8,4,2,1
// lane 0 of each 16-lane group holds the group sum.
template <int N>
__device__ __forceinline__ float row_shl_add(float x) {
  int y = __builtin_amdgcn_update_dpp(0, __float_as_int(x),
                                      0x100 | N, 0xf, 0xf, true);
  return x + __int_as_float(y);
}

// ---------------------------------------------------------------------------
// Kernel 0 (fused prep):
//  blocks 0..NB-1:        qpb[n][u] = b[u] + sum_c (query[n]·w_conv[c]) * w_q[c,u]
//  blocks NB..NB+CKC-1:   wkT[u][c] <- bf16(w_k[c][u])
__global__ void prep_kernel(const float* __restrict__ query,
                            const float* __restrict__ w_conv,
                            const float* __restrict__ w_q,
                            const float* __restrict__ bvec,
                            const float* __restrict__ w_k,
                            float* __restrict__ qpb,
                            unsigned short* __restrict__ wkT_hi) {
  const int tid = threadIdx.x;
  if (blockIdx.x >= NB) {
    const int c = blockIdx.x - NB;   // 0..255
    if (tid < UQ) wkT_hi[tid * CKC + c] = f2bf(w_k[c * UQ + tid]);
    return;
  }
  __shared__ float qr[256];
  __shared__ float qv[256];
  const int n = blockIdx.x;
  qr[tid] = query[n * 256 + tid];
  __syncthreads();
  float acc = 0.f;
  const f32x4* wrow = (const f32x4*)(w_conv + (size_t)tid * 256);
  const f32x4* q4 = (const f32x4*)qr;
#pragma unroll 8
  for (int i = 0; i < 64; ++i) {
    f32x4 wv4 = wrow[i];
    f32x4 qq = q4[i];
    acc += wv4[0] * qq[0] + wv4[1] * qq[1] + wv4[2] * qq[2] + wv4[3] * qq[3];
  }
  qv[tid] = acc;
  __syncthreads();
  if (tid < UQ) {
    float a2 = bvec[tid];
#pragma unroll 4
    for (int c = 0; c < 256; ++c) a2 += qv[c] * w_q[c * UQ + tid];
    qpb[n * UQ + tid] = a2;
  }
}

// ---------------------------------------------------------------------------
// Kernel 1: WAVE-INDEPENDENT fused kernel. grid 256 = 32 n * 8 segs; block 512
// = 8 waves; each wave owns 128 consecutive key rows (8 tiles of 16), fully
// independent: NO barriers in the main loop.
//  - w_k staged in LDS once (64KB bf16, XOR-swizzled), read as B-fragments.
//  - key loaded global->regs directly in A-fragment layout (lane: row=lane&15,
//    cols 32kt+8*(lane>>4)+j), 1 tile ahead, converted to bf16 in-register.
//  - scores: MFMA D[row=4*(lane>>4)+i][u=16g+(lane&15)]; per-row u-sum via
//    in-register slice accumulation + 16-lane DPP tree.
//  - context: lane holds row (lane&15)'s 64 cols in A regs; weight via
//    wave-private LDS bounce (no barrier); 64 f32 accumulators/lane.
__global__ __launch_bounds__(512, 1)
void fused_attn_kernel(const float* __restrict__ key,
                       const float* __restrict__ gumbel,
                       const float* __restrict__ v,
                       const float* __restrict__ qpb,
                       const unsigned short* __restrict__ wkT_hi,
                       float* __restrict__ part,
                       float* __restrict__ out_align) {
  __shared__ __align__(16) unsigned short wk_lds[UQ * CKC];  // 64KB swizzled
  __shared__ __align__(16) float wbounce[8][16];
  __shared__ __align__(16) float ctxred[8][256];             // 8KB
  __shared__ float lpart[8][4];

  const int tid = threadIdx.x;
  const int lane = tid & 63;
  const int wv = tid >> 6;      // 0..7
  const int ul = lane & 15;     // A row / B col index
  const int lg = lane >> 4;     // 0..3
  const int bid = blockIdx.x;
  const int n = bid >> 3;
  const int seg = bid & 7;

  // ---- stage w_k into LDS (swizzled), coalesced: 8 rounds x 8KB ----
  {
#pragma unroll
    for (int r = 0; r < 8; ++r) {
      const int gi = r * 512 + tid;            // 16B granule index
      const unsigned byte = (unsigned)gi * 16u;
      const unsigned u = byte >> 9;            // row (u)
      const unsigned bcol = byte & 511u;       // byte within row
      short8 w8 = *(const short8*)((const char*)wkT_hi + byte);
      *(short8*)((char*)wk_lds + ((u * 512u + bcol) ^ ((u & 7u) << 4))) = w8;
    }
  }

  // per-lane constants: v and qpb for u = 16g + ul
  float v_reg[8], q_reg[8];
#pragma unroll
  for (int g = 0; g < 8; ++g) {
    v_reg[g] = v[16 * g + ul];
    q_reg[g] = qpb[n * UQ + 16 * g + ul];
  }

  const float* keyN = key + (size_t)n * T_LEN * CKC;
  const int t_base = seg * SEG_ROWS + wv * WAVE_ROWS;
  const float* rowp = keyN + (size_t)(t_base + ul) * CKC + lg * 8;

  // prologue: tile 0 key loads + gumbel (issued before the staging barrier;
  // barrier_lgkm does not drain vmcnt, so they stay in flight)
  f32x4 stg[16];
#pragma unroll
  for (int kt = 0; kt < 8; ++kt) {
    stg[2 * kt]     = *(const f32x4*)(rowp + kt * 32);
    stg[2 * kt + 1] = *(const f32x4*)(rowp + kt * 32 + 4);
  }
  f32x4 g4 = *(const f32x4*)(gumbel + n * T_LEN + t_base + 4 * lg);

  barrier_lgkm();  // publish wk_lds (the ONLY pre-epilogue barrier)

  const unsigned axor = ((unsigned)(ul & 7)) << 4;
  const unsigned bbase = (unsigned)(ul * 512 + lg * 16);

  float ctx[64];
#pragma unroll
  for (int i2 = 0; i2 < 64; ++i2) ctx[i2] = 0.f;
  float l_part = 0.f;

  for (int tile = 0; tile < NTILES; ++tile) {
    // ---- convert staged fp32 rows -> bf16 A-fragments ----
    short8 A[8];
#pragma unroll
    for (int kt = 0; kt < 8; ++kt) {
      union { ushort4_t h[2]; short8 s8; } uf;
      uf.h[0] = pack_bf16x4(stg[2 * kt]);
      uf.h[1] = pack_bf16x4(stg[2 * kt + 1]);
      A[kt] = uf.s8;
    }
    f32x4 g4c = g4;
    // ---- issue next tile's loads (consumed next iteration: long slack) ----
    if (tile + 1 < NTILES) {
      const float* rp = rowp + (size_t)(tile + 1) * 16 * CKC;
#pragma unroll
      for (int kt = 0; kt < 8; ++kt) {
        stg[2 * kt]     = *(const f32x4*)(rp + kt * 32);
        stg[2 * kt + 1] = *(const f32x4*)(rp + kt * 32 + 4);
      }
      g4 = *(const f32x4*)(gumbel + n * T_LEN + t_base + (tile + 1) * 16 + 4 * lg);
    }

    // ---- 8 u-slices: MFMA (B from LDS) + tanh + in-register u-accumulate ----
    float sp0 = 0.f, sp1 = 0.f, sp2 = 0.f, sp3 = 0.f;
#pragma unroll
    for (int g = 0; g < 8; ++g) {
      const unsigned sb = bbase + (unsigned)(g * 8192);
      f32x4 acca = {0.f, 0.f, 0.f, 0.f};
      f32x4 accb = {0.f, 0.f, 0.f, 0.f};
#pragma unroll
      for (int kt = 0; kt < 4; ++kt) {
        short8 bf = *(const short8*)((const char*)wk_lds + ((sb + kt * 64) ^ axor));
        acca = __builtin_amdgcn_mfma_f32_16x16x32_bf16(A[kt], bf, acca, 0, 0, 0);
      }
#pragma unroll
      for (int kt = 4; kt < 8; ++kt) {
        short8 bf = *(const short8*)((const char*)wk_lds + ((sb + kt * 64) ^ axor));
        accb = __builtin_amdgcn_mfma_f32_16x16x32_bf16(A[kt], bf, accb, 0, 0, 0);
      }
      sp0 += v_reg[g] * fast_tanh(acca[0] + accb[0] + q_reg[g]);
      sp1 += v_reg[g] * fast_tanh(acca[1] + accb[1] + q_reg[g]);
      sp2 += v_reg[g] * fast_tanh(acca[2] + accb[2] + q_reg[g]);
      sp3 += v_reg[g] * fast_tanh(acca[3] + accb[3] + q_reg[g]);
    }
    // ---- per-row sums: 16-lane DPP tree (rows 4*lg+i live at lane 16*lg) ----
    sp0 = row_shl_add<8>(sp0); sp0 = row_shl_add<4>(sp0);
    sp0 = row_shl_add<2>(sp0); sp0 = row_shl_add<1>(sp0);
    sp1 = row_shl_add<8>(sp1); sp1 = row_shl_add<4>(sp1);
    sp1 = row_shl_add<2>(sp1); sp1 = row_shl_add<1>(sp1);
    sp2 = row_shl_add<8>(sp2); sp2 = row_shl_add<4>(sp2);
    sp2 = row_shl_add<2>(sp2); sp2 = row_shl_add<1>(sp2);
    sp3 = row_shl_add<8>(sp3); sp3 = row_shl_add<4>(sp3);
    sp3 = row_shl_add<2>(sp3); sp3 = row_shl_add<1>(sp3);

    // ---- softmax weights (valid at ul==0 lanes), raw scores to align ----
    const int t0c = t_base + tile * 16;
    f32x4 st4, w4;
    st4[0] = sp0 + g4c[0]; st4[1] = sp1 + g4c[1];
    st4[2] = sp2 + g4c[2]; st4[3] = sp3 + g4c[3];
    w4[0] = __expf(st4[0] - FIXED_MAX); w4[1] = __expf(st4[1] - FIXED_MAX);
    w4[2] = __expf(st4[2] - FIXED_MAX); w4[3] = __expf(st4[3] - FIXED_MAX);
    if (ul == 0) {
      *(f32x4*)(out_align + (size_t)n * T_LEN + t0c + 4 * lg) = st4;
      *(f32x4*)&wbounce[wv][4 * lg] = w4;
      l_part += (w4[0] + w4[1]) + (w4[2] + w4[3]);
    }
    // wave-private LDS bounce: compiler's lgkmcnt orders write->read in-wave
    float w_mine = wbounce[wv][ul];   // weight of this lane's A row
    // ---- context accumulate: lane's 64 cols of row (t0c+ul) ----
#pragma unroll
    for (int kt = 0; kt < 8; ++kt) {
#pragma unroll
      for (int j = 0; j < 8; ++j)
        ctx[kt * 8 + j] += w_mine * bf2f((unsigned short)A[kt][j]);
    }
  }

  // ---- per-wave epilogue: reduce ctx across the 16 rows (lanes) ----
#pragma unroll
  for (int s2 = 0; s2 < 64; ++s2) {
    ctx[s2] = row_shl_add<8>(ctx[s2]);
    ctx[s2] = row_shl_add<4>(ctx[s2]);
    ctx[s2] = row_shl_add<2>(ctx[s2]);
    ctx[s2] = row_shl_add<1>(ctx[s2]);
  }
  if (ul == 0) {
#pragma unroll
    for (int kt = 0; kt < 8; ++kt) {
      f32x4 c0, c1;
      c0[0] = ctx[kt * 8 + 0]; c0[1] = ctx[kt * 8 + 1];
      c0[2] = ctx[kt * 8 + 2]; c0[3] = ctx[kt * 8 + 3];
      c1[0] = ctx[kt * 8 + 4]; c1[1] = ctx[kt * 8 + 5];
      c1[2] = ctx[kt * 8 + 6]; c1[3] = ctx[kt * 8 + 7];
      *(f32x4*)&ctxred[wv][kt * 32 + lg * 8] = c0;
      *(f32x4*)&ctxred[wv][kt * 32 + lg * 8 + 4] = c1;
    }
    lpart[wv][lg] = l_part;
  }
  barrier_lgkm();

  // ---- block reduce over 8 waves, write partial {l, ctx[256]} ----
  float* pb = part + (size_t)bid * PART_STRIDE;
  if (tid == 0) {
    float ls = 0.f;
#pragma unroll
    for (int w2 = 0; w2 < 8; ++w2)
#pragma unroll
      for (int q2 = 0; q2 < 4; ++q2) ls += lpart[w2][q2];
    pb[0] = ls;
  }
  if (tid < 256) {
    float cs = 0.f;
#pragma unroll
    for (int w2 = 0; w2 < 8; ++w2) cs += ctxred[w2][tid];
    pb[2 + tid] = cs;
  }
}

// ---------------------------------------------------------------------------
// Kernel 2: combine per-seg partials -> context; in-place score -> align.
// grid NB*8: block (n, seg); seg 0 also writes ctx.
__global__ void combine_kernel(const float* __restrict__ part,
                               float* __restrict__ out_ctx,
                               float* __restrict__ out_align) {
  __shared__ float lp[NSEG];
  const int n = blockIdx.x >> 3;
  const int seg = blockIdx.x & 7;
  const int tid = threadIdx.x;
  if (tid < NSEG)
    lp[tid] = part[(size_t)(n * NSEG + tid) * PART_STRIDE];
  __syncthreads();
  float lg = 0.f;
#pragma unroll
  for (int j = 0; j < NSEG; ++j) lg += lp[j];
  const float inv = 1.0f / lg;
  if (seg == 0) {
    float ca = 0.f;
#pragma unroll
    for (int j = 0; j < NSEG; ++j)
      ca += part[(size_t)(n * NSEG + j) * PART_STRIDE + 2 + tid];
    out_ctx[n * 256 + tid] = ca * inv;
  }
  const int tb = seg * (T_LEN / 8);
#pragma unroll
  for (int i = 0; i < T_LEN / 8 / 256; ++i) {
    const int t = tb + i * 256 + tid;
    float s = out_align[(size_t)n * T_LEN + t];
    out_align[(size_t)n * T_LEN + t] = __expf(s - FIXED_MAX) * inv;
  }
}

// ---------------------------------------------------------------------------
extern "C" void kernel_launch(void* const* d_in, const int* in_sizes, int n_in,
                              void* d_out, int out_size, void* d_ws, size_t ws_size,
                              hipStream_t stream) {
  const float* query = (const float*)d_in[0];
  const float* key = (const float*)d_in[1];
  const float* w_conv = (const float*)d_in[2];
  const float* w_q = (const float*)d_in[3];
  const float* w_k = (const float*)d_in[4];
  const float* v = (const float*)d_in[5];
  const float* b = (const float*)d_in[6];
  const float* gumbel = (const float*)d_in[7];

  float* out = (float*)d_out;
  float* out_ctx = out;                 // 32*256
  float* out_align = out + NB * CKC;    // 32*8192

  char* ws = (char*)d_ws;
  float* qpb = (float*)ws;                                    // 16 KB
  unsigned short* wkT_hi = (unsigned short*)(ws + 16 * 1024); // 64 KB
  float* part = (float*)(ws + 144 * 1024);                    // 256*258*4 B

  prep_kernel<<<dim3(NB + CKC), dim3(256), 0, stream>>>(
      query, w_conv, w_q, b, w_k, qpb, wkT_hi);
  fused_attn_kernel<<<dim3(NB * NSEG), dim3(512), 0, stream>>>(
      key, gumbel, v, qpb, wkT_hi, part, out_align);
  combine_kernel<<<dim3(NB * 8), dim3(256), 0, stream>>>(part, out_ctx, out_align);
}

// Round 12
// 137.029 us; speedup vs baseline: 1.9683x; 1.9683x over previous
//
#include <hip/hip_runtime.h>
#include <hip/hip_bf16.h>

// Problem constants
#define NB 32
#define T_LEN 8192
#define CKC 256
#define UQ 128
#define NCHUNK 64
#define ROWS_PER_CHUNK 128   // T_LEN / NCHUNK
#define STEP 16
#define NSTEPS 8             // ROWS_PER_CHUNK / STEP
#define PART_STRIDE 258
#define FIXED_MAX 25.0f      // scores provably < 25; exp(st-25) in [e^-60, e^-2]

typedef short short8 __attribute__((ext_vector_type(8)));
typedef float f32x4 __attribute__((ext_vector_type(4)));
typedef unsigned short ushort4_t __attribute__((ext_vector_type(4)));

__device__ __forceinline__ unsigned short f2bf(float x) {
  union { float f; unsigned u; } un; un.f = x;
  unsigned r = un.u + 0x7FFFu + ((un.u >> 16) & 1u);
  return (unsigned short)(r >> 16);
}
__device__ __forceinline__ float bf2f(unsigned short h) {
  union { unsigned u; float f; } un; un.u = ((unsigned)h) << 16;
  return un.f;
}
__device__ __forceinline__ float fast_tanh(float x) {
  float e = __expf(2.0f * x);
  return 1.0f - 2.0f / (e + 1.0f);   // saturates correctly for |x| large
}
__device__ __forceinline__ ushort4_t pack_bf16x4(f32x4 x) {
  union { __hip_bfloat162 h; unsigned short u[2]; } a, b;
  a.h = __float22bfloat162_rn(make_float2(x[0], x[1]));
  b.h = __float22bfloat162_rn(make_float2(x[2], x[3]));
  ushort4_t r; r[0] = a.u[0]; r[1] = a.u[1]; r[2] = b.u[0]; r[3] = b.u[1];
  return r;
}
// Publishing barrier: waits only this wave's LDS ops, does NOT drain vmcnt.
__device__ __forceinline__ void barrier_lgkm() {
  asm volatile("s_waitcnt lgkmcnt(0)" ::: "memory");
  __builtin_amdgcn_s_barrier();
}
// Pure-VALU 16-lane reduction step (DPP row_shl, 0-fill).
template <int N>
__device__ __forceinline__ float row_shl_add(float x) {
  int y = __builtin_amdgcn_update_dpp(0, __float_as_int(x),
                                      0x100 | N, 0xf, 0xf, true);
  return x + __int_as_float(y);
}
// Keep a value live without cost (anti-DCE, rule #17).
__device__ __forceinline__ void sinkf(float x) { asm volatile("" :: "v"(x)); }

// ---------------------------------------------------------------------------
// Kernel 0 (fused prep):
__global__ void prep_kernel(const float* __restrict__ query,
                            const float* __restrict__ w_conv,
                            const float* __restrict__ w_q,
                            const float* __restrict__ bvec,
                            const float* __restrict__ w_k,
                            float* __restrict__ qpb,
                            unsigned short* __restrict__ wkT_hi) {
  const int tid = threadIdx.x;
  if (blockIdx.x >= NB) {
    const int c = blockIdx.x - NB;   // 0..255
    if (tid < UQ) wkT_hi[tid * CKC + c] = f2bf(w_k[c * UQ + tid]);
    return;
  }
  __shared__ float qr[256];
  __shared__ float qv[256];
  const int n = blockIdx.x;
  qr[tid] = query[n * 256 + tid];
  __syncthreads();
  float acc = 0.f;
  const f32x4* wrow = (const f32x4*)(w_conv + (size_t)tid * 256);
  const f32x4* q4 = (const f32x4*)qr;
#pragma unroll 8
  for (int i = 0; i < 64; ++i) {
    f32x4 wv4 = wrow[i];
    f32x4 qq = q4[i];
    acc += wv4[0] * qq[0] + wv4[1] * qq[1] + wv4[2] * qq[2] + wv4[3] * qq[3];
  }
  qv[tid] = acc;
  __syncthreads();
  if (tid < UQ) {
    float a2 = bvec[tid];
#pragma unroll 4
    for (int c = 0; c < 256; ++c) a2 += qv[c] * w_q[c * UQ + tid];
    qpb[n * UQ + tid] = a2;
  }
}

// ---------------------------------------------------------------------------
// Kernel 1 (templated ablation): V=0 full (R10 code path), V=1 stage-only,
// V=2 +ds_read+MFMA (sunk), V=3 +tanh+DPP+spart-write (no exchange/softmax).
template <int V>
__global__ __launch_bounds__(512, 2)
void fused_attn_kernel(const float* __restrict__ key,
                       const float* __restrict__ gumbel,
                       const float* __restrict__ v,
                       const float* __restrict__ qpb,
                       const unsigned short* __restrict__ wkT_hi,
                       float* __restrict__ part,
                       float* __restrict__ out_align) {
  __shared__ __align__(16) unsigned short ldsHi[2][STEP * CKC]; // 2 x 8KB
  __shared__ __align__(16) float spart_t[2][STEP][8];           // [buf][row][wave]
  __shared__ __align__(16) float ctx8[8][256];                  // epilogue reduce
  __shared__ float gbuf[ROWS_PER_CHUNK];
  __shared__ float lred[8];

  const int tid = threadIdx.x;
  const int lane = tid & 63;
  const int wv = tid >> 6;  // 0..7
  const int bid = blockIdx.x;
  const int n = bid >> 6;
  const int chunk = bid & 63;
  const int t0 = chunk * ROWS_PER_CHUNK;

  if (tid < ROWS_PER_CHUNK) gbuf[tid] = gumbel[n * T_LEN + t0 + tid];

  const int u = wv * 16 + (lane & 15);
  const float qpb_u = qpb[n * UQ + u];
  const float v_u = v[u];

  short8 bhi[8];
  {
    const int koff = (lane >> 4) * 8;
#pragma unroll
    for (int kt = 0; kt < 8; ++kt)
      bhi[kt] = *(const short8*)(wkT_hi + (size_t)u * CKC + kt * 32 + koff);
  }

  const int c40 = (tid & 63) << 2;
  const unsigned off0 = ((unsigned)(wv * 512 + c40 * 2)) ^ ((unsigned)wv << 4);
  const unsigned off1 = ((unsigned)((wv + 8) * 512 + c40 * 2)) ^ ((unsigned)wv << 4);

  const int ar = lane & 15;
  const unsigned axor = ((unsigned)(ar & 7)) << 4;
  const unsigned abase = (unsigned)(ar * 512 + (lane >> 4) * 16);

  const float* keyN = key + (size_t)n * T_LEN * CKC;

  f32x4 cur0, cur1, nxt0, nxt1, nx20, nx21;
  cur0 = *(const f32x4*)(keyN + (size_t)(t0 + wv) * CKC + c40);
  cur1 = *(const f32x4*)(keyN + (size_t)(t0 + wv + 8) * CKC + c40);
  nxt0 = *(const f32x4*)(keyN + (size_t)(t0 + STEP + wv) * CKC + c40);
  nxt1 = *(const f32x4*)(keyN + (size_t)(t0 + STEP + wv + 8) * CKC + c40);

  ushort4_t pv0, pv1;
  float l_acc = 0.0f;
  f32x4 acc0 = {0.f, 0.f, 0.f, 0.f};
  f32x4 acc1 = {0.f, 0.f, 0.f, 0.f};

  for (int s = 0; s < NSTEPS; ++s) {
    const int p = s & 1;
    // ---- stage cur -> LDS buf p (bf16); keep packed copy ----
    ushort4_t h0 = pack_bf16x4(cur0);
    ushort4_t h1 = pack_bf16x4(cur1);
    *(ushort4_t*)((char*)&ldsHi[p][0] + off0) = h0;
    *(ushort4_t*)((char*)&ldsHi[p][0] + off1) = h1;
    // ---- prefetch tile s+2 ----
    if (s + 2 < NSTEPS) {
      const int ts = t0 + (s + 2) * STEP;
      nx20 = *(const f32x4*)(keyN + (size_t)(ts + wv) * CKC + c40);
      nx21 = *(const f32x4*)(keyN + (size_t)(ts + wv + 8) * CKC + c40);
    }
    barrier_lgkm();  // the ONLY barrier per step

    if constexpr (V != 1) {
      // ---- MFMA: 2 chains of 4 ----
      f32x4 acca = {0.f, 0.f, 0.f, 0.f};
      f32x4 accb = {0.f, 0.f, 0.f, 0.f};
#pragma unroll
      for (int kt = 0; kt < 4; ++kt) {
        unsigned off = (abase + (unsigned)(kt * 64)) ^ axor;
        short8 kf = *(const short8*)((const char*)&ldsHi[p][0] + off);
        acca = __builtin_amdgcn_mfma_f32_16x16x32_bf16(kf, bhi[kt], acca, 0, 0, 0);
      }
#pragma unroll
      for (int kt = 4; kt < 8; ++kt) {
        unsigned off = (abase + (unsigned)(kt * 64)) ^ axor;
        short8 kf = *(const short8*)((const char*)&ldsHi[p][0] + off);
        accb = __builtin_amdgcn_mfma_f32_16x16x32_bf16(kf, bhi[kt], accb, 0, 0, 0);
      }
      if constexpr (V == 2) {
#pragma unroll
        for (int i = 0; i < 4; ++i) { sinkf(acca[i]); sinkf(accb[i]); }
      } else {
        // ---- tanh + DPP tree + spart write ----
        float sv[4];
#pragma unroll
        for (int i = 0; i < 4; ++i)
          sv[i] = v_u * fast_tanh(acca[i] + accb[i] + qpb_u);
#pragma unroll
        for (int i = 0; i < 4; ++i) {
          sv[i] = row_shl_add<8>(sv[i]);
          sv[i] = row_shl_add<4>(sv[i]);
          sv[i] = row_shl_add<2>(sv[i]);
          sv[i] = row_shl_add<1>(sv[i]);
        }
        if ((lane & 15) == 0) {
          const int g = lane >> 4;
#pragma unroll
          for (int i = 0; i < 4; ++i) spart_t[p][g * 4 + i][wv] = sv[i];
        }
      }
    }

    if constexpr (V == 0) {
      // ---- deferred softmax + context for tile s-1 ----
      if (s > 0) {
        const int q = p ^ 1;
        const f32x4* sp0 = (const f32x4*)&spart_t[q][wv][0];
        const f32x4* sp1 = (const f32x4*)&spart_t[q][wv + 8][0];
        f32x4 s0 = sp0[0] + sp0[1];
        f32x4 s1 = sp1[0] + sp1[1];
        float st0 = gbuf[(s - 1) * STEP + wv] + ((s0[0] + s0[1]) + (s0[2] + s0[3]));
        float st1 = gbuf[(s - 1) * STEP + wv + 8] + ((s1[0] + s1[1]) + (s1[2] + s1[3]));
        float w0 = __expf(st0 - FIXED_MAX);
        float w1 = __expf(st1 - FIXED_MAX);
#pragma unroll
        for (int j = 0; j < 4; ++j) {
          acc0[j] += w0 * bf2f(pv0[j]);
          acc1[j] += w1 * bf2f(pv1[j]);
        }
        l_acc += w0 + w1;
        if (wv == 0 && lane < 16) {
          const f32x4* sp = (const f32x4*)&spart_t[q][lane][0];
          f32x4 ss = sp[0] + sp[1];
          float st = gbuf[(s - 1) * STEP + lane] + ((ss[0] + ss[1]) + (ss[2] + ss[3]));
          out_align[(size_t)n * T_LEN + t0 + (s - 1) * STEP + lane] = st;
        }
      }
    }
    // rotate pipeline registers
    pv0 = h0; pv1 = h1;
    cur0 = nxt0; cur1 = nxt1;
    nxt0 = nx20; nxt1 = nx21;
  }

  if constexpr (V == 0) {
    // ---- epilogue: softmax + context for the last tile ----
    barrier_lgkm();
    {
      const int q = (NSTEPS - 1) & 1;
      const f32x4* sp0 = (const f32x4*)&spart_t[q][wv][0];
      const f32x4* sp1 = (const f32x4*)&spart_t[q][wv + 8][0];
      f32x4 s0 = sp0[0] + sp0[1];
      f32x4 s1 = sp1[0] + sp1[1];
      float st0 = gbuf[(NSTEPS - 1) * STEP + wv] + ((s0[0] + s0[1]) + (s0[2] + s0[3]));
      float st1 = gbuf[(NSTEPS - 1) * STEP + wv + 8] + ((s1[0] + s1[1]) + (s1[2] + s1[3]));
      float w0 = __expf(st0 - FIXED_MAX);
      float w1 = __expf(st1 - FIXED_MAX);
#pragma unroll
      for (int j = 0; j < 4; ++j) {
        acc0[j] += w0 * bf2f(pv0[j]);
        acc1[j] += w1 * bf2f(pv1[j]);
      }
      l_acc += w0 + w1;
      if (wv == 0 && lane < 16) {
        const f32x4* sp = (const f32x4*)&spart_t[q][lane][0];
        f32x4 ss = sp[0] + sp[1];
        float st = gbuf[(NSTEPS - 1) * STEP + lane] + ((ss[0] + ss[1]) + (ss[2] + ss[3]));
        out_align[(size_t)n * T_LEN + t0 + (NSTEPS - 1) * STEP + lane] = st;
      }
    }
    // ---- cross-wave reduce, write partial {l, ctx[256]} ----
    if (lane == 0) lred[wv] = l_acc;
    {
      f32x4 c4;
#pragma unroll
      for (int j = 0; j < 4; ++j) c4[j] = acc0[j] + acc1[j];
      *(f32x4*)&ctx8[wv][c40] = c4;
    }
    barrier_lgkm();
    float* pb = part + (size_t)bid * PART_STRIDE;
    if (tid == 0) {
      float ls = 0.f;
#pragma unroll
      for (int w2 = 0; w2 < 8; ++w2) ls += lred[w2];
      pb[0] = ls;
    }
    if (tid < 256) {
      float cs = 0.f;
#pragma unroll
      for (int w2 = 0; w2 < 8; ++w2) cs += ctx8[w2][tid];
      pb[2 + tid] = cs;
    }
  }
}

// ---------------------------------------------------------------------------
// Kernel 2: combine per-chunk partials -> context; in-place score -> align.
__global__ void combine_kernel(const float* __restrict__ part,
                               float* __restrict__ out_ctx,
                               float* __restrict__ out_align) {
  __shared__ float lp[NCHUNK];
  const int n = blockIdx.x >> 3;
  const int seg = blockIdx.x & 7;
  const int tid = threadIdx.x;
  if (tid < NCHUNK)
    lp[tid] = part[(size_t)(n * NCHUNK + tid) * PART_STRIDE];
  __syncthreads();
  float lg = 0.f;
#pragma unroll 8
  for (int j = 0; j < NCHUNK; ++j) lg += lp[j];
  const float inv = 1.0f / lg;
  if (seg == 0) {
    float ca = 0.f;
    for (int j = 0; j < NCHUNK; ++j)
      ca += part[(size_t)(n * NCHUNK + j) * PART_STRIDE + 2 + tid];
    out_ctx[n * 256 + tid] = ca * inv;
  }
  const int tb = seg * (T_LEN / 8);
#pragma unroll
  for (int i = 0; i < T_LEN / 8 / 256; ++i) {
    const int t = tb + i * 256 + tid;
    float s = out_align[(size_t)n * T_LEN + t];
    out_align[(size_t)n * T_LEN + t] = __expf(s - FIXED_MAX) * inv;
  }
}

// ---------------------------------------------------------------------------
extern "C" void kernel_launch(void* const* d_in, const int* in_sizes, int n_in,
                              void* d_out, int out_size, void* d_ws, size_t ws_size,
                              hipStream_t stream) {
  const float* query = (const float*)d_in[0];
  const float* key = (const float*)d_in[1];
  const float* w_conv = (const float*)d_in[2];
  const float* w_q = (const float*)d_in[3];
  const float* w_k = (const float*)d_in[4];
  const float* v = (const float*)d_in[5];
  const float* b = (const float*)d_in[6];
  const float* gumbel = (const float*)d_in[7];

  float* out = (float*)d_out;
  float* out_ctx = out;                 // 32*256
  float* out_align = out + NB * CKC;    // 32*8192

  char* ws = (char*)d_ws;
  float* qpb = (float*)ws;                                    // 16 KB
  unsigned short* wkT_hi = (unsigned short*)(ws + 16 * 1024); // 64 KB
  float* part = (float*)(ws + 144 * 1024);                    // 2048*258*4 B

  prep_kernel<<<dim3(NB + CKC), dim3(256), 0, stream>>>(
      query, w_conv, w_q, b, w_k, qpb, wkT_hi);

  // --- ablation probes (quarter grid; outputs fully overwritten below) ---
  fused_attn_kernel<1><<<dim3(512), dim3(512), 0, stream>>>(
      key, gumbel, v, qpb, wkT_hi, part, out_align);
  fused_attn_kernel<2><<<dim3(512), dim3(512), 0, stream>>>(
      key, gumbel, v, qpb, wkT_hi, part, out_align);
  fused_attn_kernel<3><<<dim3(512), dim3(512), 0, stream>>>(
      key, gumbel, v, qpb, wkT_hi, part, out_align);

  // --- real kernel (full grid) ---
  fused_attn_kernel<0><<<dim3(NB * NCHUNK), dim3(512), 0, stream>>>(
      key, gumbel, v, qpb, wkT_hi, part, out_align);
  combine_kernel<<<dim3(NB * 8), dim3(256), 0, stream>>>(part, out_ctx, out_align);
}

// Round 13
// 97.453 us; speedup vs baseline: 2.7677x; 1.4061x over previous
//
#include <hip/hip_runtime.h>
#include <hip/hip_bf16.h>

// Problem constants
#define NB 32
#define T_LEN 8192
#define CKC 256
#define UQ 128
#define NCHUNK 64
#define ROWS_PER_CHUNK 128   // T_LEN / NCHUNK
#define STEP 16
#define NPAIRS 4             // pairs of 16-row tiles; 32 rows per barrier window
#define PART_STRIDE 258
#define FIXED_MAX 25.0f      // scores provably < 25; exp(st-25) in [e^-60, e^-2]

typedef short short8 __attribute__((ext_vector_type(8)));
typedef float f32x4 __attribute__((ext_vector_type(4)));
typedef unsigned short ushort4_t __attribute__((ext_vector_type(4)));

__device__ __forceinline__ unsigned short f2bf(float x) {
  union { float f; unsigned u; } un; un.f = x;
  unsigned r = un.u + 0x7FFFu + ((un.u >> 16) & 1u);
  return (unsigned short)(r >> 16);
}
__device__ __forceinline__ float bf2f(unsigned short h) {
  union { unsigned u; float f; } un; un.u = ((unsigned)h) << 16;
  return un.f;
}
__device__ __forceinline__ float fast_tanh(float x) {
  float e = __expf(2.0f * x);
  return 1.0f - 2.0f / (e + 1.0f);   // saturates correctly for |x| large
}
__device__ __forceinline__ ushort4_t pack_bf16x4(f32x4 x) {
  union { __hip_bfloat162 h; unsigned short u[2]; } a, b;
  a.h = __float22bfloat162_rn(make_float2(x[0], x[1]));
  b.h = __float22bfloat162_rn(make_float2(x[2], x[3]));
  ushort4_t r; r[0] = a.u[0]; r[1] = a.u[1]; r[2] = b.u[0]; r[3] = b.u[1];
  return r;
}
// Publishing barrier: waits only this wave's LDS ops, does NOT drain vmcnt.
__device__ __forceinline__ void barrier_lgkm() {
  asm volatile("s_waitcnt lgkmcnt(0)" ::: "memory");
  __builtin_amdgcn_s_barrier();
}
// Pure-VALU 16-lane reduction step (DPP row_shl, 0-fill).
template <int N>
__device__ __forceinline__ float row_shl_add(float x) {
  int y = __builtin_amdgcn_update_dpp(0, __float_as_int(x),
                                      0x100 | N, 0xf, 0xf, true);
  return x + __int_as_float(y);
}
__device__ __forceinline__ float hsum4(f32x4 x) {
  return (x[0] + x[1]) + (x[2] + x[3]);
}

// ---------------------------------------------------------------------------
// Kernel 0 (fused prep):
__global__ void prep_kernel(const float* __restrict__ query,
                            const float* __restrict__ w_conv,
                            const float* __restrict__ w_q,
                            const float* __restrict__ bvec,
                            const float* __restrict__ w_k,
                            float* __restrict__ qpb,
                            unsigned short* __restrict__ wkT_hi) {
  const int tid = threadIdx.x;
  if (blockIdx.x >= NB) {
    const int c = blockIdx.x - NB;   // 0..255
    if (tid < UQ) wkT_hi[tid * CKC + c] = f2bf(w_k[c * UQ + tid]);
    return;
  }
  __shared__ float qr[256];
  __shared__ float qv[256];
  const int n = blockIdx.x;
  qr[tid] = query[n * 256 + tid];
  __syncthreads();
  float acc = 0.f;
  const f32x4* wrow = (const f32x4*)(w_conv + (size_t)tid * 256);
  const f32x4* q4 = (const f32x4*)qr;
#pragma unroll 8
  for (int i = 0; i < 64; ++i) {
    f32x4 wv4 = wrow[i];
    f32x4 qq = q4[i];
    acc += wv4[0] * qq[0] + wv4[1] * qq[1] + wv4[2] * qq[2] + wv4[3] * qq[3];
  }
  qv[tid] = acc;
  __syncthreads();
  if (tid < UQ) {
    float a2 = bvec[tid];
#pragma unroll 4
    for (int c = 0; c < 256; ++c) a2 += qv[c] * w_q[c * UQ + tid];
    qpb[n * UQ + tid] = a2;
  }
}

// ---------------------------------------------------------------------------
// Kernel 1: fused kernel, PAIR-processed. grid 2048 = 32 n * 64 chunks; block
// 512 = 8 waves; wave w owns u in [16w,16w+16). ONE barrier per 32 rows:
// stage tiles {2p,2p+1} -> barrier -> MFMA+DPP+spart both tiles -> deferred
// softmax+context for pair p-1. Each wave writes its own rows' raw scores
// (no divergent wave-0 block). Prefetch: pair p+1 issued pre-barrier.
__global__ __launch_bounds__(512, 2)
void fused_attn_kernel(const float* __restrict__ key,
                       const float* __restrict__ gumbel,
                       const float* __restrict__ v,
                       const float* __restrict__ qpb,
                       const unsigned short* __restrict__ wkT_hi,
                       float* __restrict__ part,
                       float* __restrict__ out_align) {
  __shared__ __align__(16) unsigned short ldsHi[2][2][STEP * CKC]; // 4 x 8KB
  __shared__ __align__(16) float spart_t[2][2][STEP][8]; // [pair][tile][row][wv]
  __shared__ __align__(16) float ctx8[8][256];           // epilogue reduce
  __shared__ float gbuf[ROWS_PER_CHUNK];
  __shared__ float lred[8];

  const int tid = threadIdx.x;
  const int lane = tid & 63;
  const int wv = tid >> 6;  // 0..7
  const int bid = blockIdx.x;
  const int n = bid >> 6;
  const int chunk = bid & 63;
  const int t0 = chunk * ROWS_PER_CHUNK;

  // gumbel chunk -> LDS (published by the first in-loop barrier)
  if (tid < ROWS_PER_CHUNK) gbuf[tid] = gumbel[n * T_LEN + t0 + tid];

  // lane-fixed u (C/D col = lane&15): D[key_row][u]
  const int u = wv * 16 + (lane & 15);
  const float qpb_u = qpb[n * UQ + u];
  const float v_u = v[u];

  // B fragments (w_k) in registers: k = kt*32 + 8*(lane>>4) + j, col = u
  short8 bhi[8];
  {
    const int koff = (lane >> 4) * 8;
#pragma unroll
    for (int kt = 0; kt < 8; ++kt)
      bhi[kt] = *(const short8*)(wkT_hi + (size_t)u * CKC + kt * 32 + koff);
  }

  // staging geometry (tile-local): rows wv, wv+8; float4 cols c40..c40+3
  const int c40 = (tid & 63) << 2;
  const unsigned off0 = ((unsigned)(wv * 512 + c40 * 2)) ^ ((unsigned)wv << 4);
  const unsigned off1 = ((unsigned)((wv + 8) * 512 + c40 * 2)) ^ ((unsigned)wv << 4);

  // A-fragment (key) read offsets (tile-local)
  const int ar = lane & 15;
  const unsigned axor = ((unsigned)(ar & 7)) << 4;
  const unsigned abase = (unsigned)(ar * 512 + (lane >> 4) * 16);

  const float* keyN = key + (size_t)n * T_LEN * CKC;

  // cur = pair pr rows: [tileA row wv, tileA row wv+8, tileB row wv, tileB wv+8]
  f32x4 cur[4];
  cur[0] = *(const f32x4*)(keyN + (size_t)(t0 + wv) * CKC + c40);
  cur[1] = *(const f32x4*)(keyN + (size_t)(t0 + wv + 8) * CKC + c40);
  cur[2] = *(const f32x4*)(keyN + (size_t)(t0 + 16 + wv) * CKC + c40);
  cur[3] = *(const f32x4*)(keyN + (size_t)(t0 + 16 + wv + 8) * CKC + c40);

  ushort4_t pv[4];                    // packed bf16 rows of pair pr-1
  float l_acc = 0.0f;
  f32x4 acc0 = {0.f, 0.f, 0.f, 0.f};  // context accum, row-slot wv
  f32x4 acc1 = {0.f, 0.f, 0.f, 0.f};  // context accum, row-slot wv+8

#pragma unroll
  for (int pr = 0; pr < NPAIRS; ++pr) {
    const int p = pr & 1;
    // ---- stage pair pr -> LDS (bf16); keep packed copies ----
    ushort4_t h[4];
#pragma unroll
    for (int j = 0; j < 4; ++j) h[j] = pack_bf16x4(cur[j]);
    *(ushort4_t*)((char*)&ldsHi[p][0][0] + off0) = h[0];
    *(ushort4_t*)((char*)&ldsHi[p][0][0] + off1) = h[1];
    *(ushort4_t*)((char*)&ldsHi[p][1][0] + off0) = h[2];
    *(ushort4_t*)((char*)&ldsHi[p][1][0] + off1) = h[3];
    // ---- issue pair pr+1 loads (consumed next pair-top: ~1 body slack) ----
    if (pr + 1 < NPAIRS) {
      const int tb = t0 + (pr + 1) * 32;
      cur[0] = *(const f32x4*)(keyN + (size_t)(tb + wv) * CKC + c40);
      cur[1] = *(const f32x4*)(keyN + (size_t)(tb + wv + 8) * CKC + c40);
      cur[2] = *(const f32x4*)(keyN + (size_t)(tb + 16 + wv) * CKC + c40);
      cur[3] = *(const f32x4*)(keyN + (size_t)(tb + 16 + wv + 8) * CKC + c40);
    }
    barrier_lgkm();  // the ONLY barrier per 32 rows; does NOT drain vmcnt

    // ---- 2 tiles: ds_read + MFMA (16 independent pairs) + tanh + DPP ----
#pragma unroll
    for (int tl = 0; tl < 2; ++tl) {
      const char* base = (const char*)&ldsHi[p][tl][0];
      f32x4 acca = {0.f, 0.f, 0.f, 0.f};
      f32x4 accb = {0.f, 0.f, 0.f, 0.f};
#pragma unroll
      for (int kt = 0; kt < 4; ++kt) {
        short8 kf = *(const short8*)(base + ((abase + (unsigned)(kt * 64)) ^ axor));
        acca = __builtin_amdgcn_mfma_f32_16x16x32_bf16(kf, bhi[kt], acca, 0, 0, 0);
      }
#pragma unroll
      for (int kt = 4; kt < 8; ++kt) {
        short8 kf = *(const short8*)(base + ((abase + (unsigned)(kt * 64)) ^ axor));
        accb = __builtin_amdgcn_mfma_f32_16x16x32_bf16(kf, bhi[kt], accb, 0, 0, 0);
      }
      float sv[4];
#pragma unroll
      for (int i = 0; i < 4; ++i)
        sv[i] = v_u * fast_tanh(acca[i] + accb[i] + qpb_u);
#pragma unroll
      for (int i = 0; i < 4; ++i) {
        sv[i] = row_shl_add<8>(sv[i]);
        sv[i] = row_shl_add<4>(sv[i]);
        sv[i] = row_shl_add<2>(sv[i]);
        sv[i] = row_shl_add<1>(sv[i]);
      }
      if ((lane & 15) == 0) {
        const int g = lane >> 4;
#pragma unroll
        for (int i = 0; i < 4; ++i) spart_t[p][tl][g * 4 + i][wv] = sv[i];
      }
    }

    // ---- deferred softmax + context for pair pr-1 (spart buf p^1) ----
    if (pr > 0) {
      const int q = p ^ 1;
#pragma unroll
      for (int tl = 0; tl < 2; ++tl) {
        const int rbase = (pr - 1) * 32 + tl * 16;
        const f32x4* sp0 = (const f32x4*)&spart_t[q][tl][wv][0];
        const f32x4* sp1 = (const f32x4*)&spart_t[q][tl][wv + 8][0];
        float st0 = gbuf[rbase + wv] + hsum4(sp0[0] + sp0[1]);
        float st1 = gbuf[rbase + wv + 8] + hsum4(sp1[0] + sp1[1]);
        float w0 = __expf(st0 - FIXED_MAX);
        float w1 = __expf(st1 - FIXED_MAX);
        const ushort4_t pva = pv[tl * 2 + 0];
        const ushort4_t pvb = pv[tl * 2 + 1];
#pragma unroll
        for (int j = 0; j < 4; ++j) {
          acc0[j] += w0 * bf2f(pva[j]);
          acc1[j] += w1 * bf2f(pvb[j]);
        }
        l_acc += w0 + w1;
        if (lane == 0) {  // st0/st1 wave-uniform: this wave owns these rows
          out_align[(size_t)n * T_LEN + t0 + rbase + wv] = st0;
          out_align[(size_t)n * T_LEN + t0 + rbase + wv + 8] = st1;
        }
      }
    }
    // rotate packed rows
#pragma unroll
    for (int j = 0; j < 4; ++j) pv[j] = h[j];
  }

  // ---- epilogue: softmax + context for the last pair ----
  barrier_lgkm();
  {
    const int q = (NPAIRS - 1) & 1;
#pragma unroll
    for (int tl = 0; tl < 2; ++tl) {
      const int rbase = (NPAIRS - 1) * 32 + tl * 16;
      const f32x4* sp0 = (const f32x4*)&spart_t[q][tl][wv][0];
      const f32x4* sp1 = (const f32x4*)&spart_t[q][tl][wv + 8][0];
      float st0 = gbuf[rbase + wv] + hsum4(sp0[0] + sp0[1]);
      float st1 = gbuf[rbase + wv + 8] + hsum4(sp1[0] + sp1[1]);
      float w0 = __expf(st0 - FIXED_MAX);
      float w1 = __expf(st1 - FIXED_MAX);
      const ushort4_t pva = pv[tl * 2 + 0];
      const ushort4_t pvb = pv[tl * 2 + 1];
#pragma unroll
      for (int j = 0; j < 4; ++j) {
        acc0[j] += w0 * bf2f(pva[j]);
        acc1[j] += w1 * bf2f(pvb[j]);
      }
      l_acc += w0 + w1;
      if (lane == 0) {
        out_align[(size_t)n * T_LEN + t0 + rbase + wv] = st0;
        out_align[(size_t)n * T_LEN + t0 + rbase + wv + 8] = st1;
      }
    }
  }

  // ---- cross-wave reduce, write partial {l, ctx[256]} ----
  if (lane == 0) lred[wv] = l_acc;
  {
    f32x4 c4;
#pragma unroll
    for (int j = 0; j < 4; ++j) c4[j] = acc0[j] + acc1[j];
    *(f32x4*)&ctx8[wv][c40] = c4;
  }
  barrier_lgkm();
  float* pb = part + (size_t)bid * PART_STRIDE;
  if (tid == 0) {
    float ls = 0.f;
#pragma unroll
    for (int w2 = 0; w2 < 8; ++w2) ls += lred[w2];
    pb[0] = ls;
  }
  if (tid < 256) {
    float cs = 0.f;
#pragma unroll
    for (int w2 = 0; w2 < 8; ++w2) cs += ctx8[w2][tid];
    pb[2 + tid] = cs;
  }
}

// ---------------------------------------------------------------------------
// Kernel 2: combine per-chunk partials -> context; in-place score -> align.
__global__ void combine_kernel(const float* __restrict__ part,
                               float* __restrict__ out_ctx,
                               float* __restrict__ out_align) {
  __shared__ float lp[NCHUNK];
  const int n = blockIdx.x >> 3;
  const int seg = blockIdx.x & 7;
  const int tid = threadIdx.x;
  if (tid < NCHUNK)
    lp[tid] = part[(size_t)(n * NCHUNK + tid) * PART_STRIDE];
  __syncthreads();
  float lg = 0.f;
#pragma unroll 8
  for (int j = 0; j < NCHUNK; ++j) lg += lp[j];
  const float inv = 1.0f / lg;
  if (seg == 0) {
    float ca = 0.f;
    for (int j = 0; j < NCHUNK; ++j)
      ca += part[(size_t)(n * NCHUNK + j) * PART_STRIDE + 2 + tid];
    out_ctx[n * 256 + tid] = ca * inv;
  }
  const int tb = seg * (T_LEN / 8);
#pragma unroll
  for (int i = 0; i < T_LEN / 8 / 256; ++i) {
    const int t = tb + i * 256 + tid;
    float s = out_align[(size_t)n * T_LEN + t];
    out_align[(size_t)n * T_LEN + t] = __expf(s - FIXED_MAX) * inv;
  }
}

// ---------------------------------------------------------------------------
extern "C" void kernel_launch(void* const* d_in, const int* in_sizes, int n_in,
                              void* d_out, int out_size, void* d_ws, size_t ws_size,
                              hipStream_t stream) {
  const float* query = (const float*)d_in[0];
  const float* key = (const float*)d_in[1];
  const float* w_conv = (const float*)d_in[2];
  const float* w_q = (const float*)d_in[3];
  const float* w_k = (const float*)d_in[4];
  const float* v = (const float*)d_in[5];
  const float* b = (const float*)d_in[6];
  const float* gumbel = (const float*)d_in[7];

  float* out = (float*)d_out;
  float* out_ctx = out;                 // 32*256
  float* out_align = out + NB * CKC;    // 32*8192

  char* ws = (char*)d_ws;
  float* qpb = (float*)ws;                                    // 16 KB
  unsigned short* wkT_hi = (unsigned short*)(ws + 16 * 1024); // 64 KB
  float* part = (float*)(ws + 144 * 1024);                    // 2048*258*4 B

  prep_kernel<<<dim3(NB + CKC), dim3(256), 0, stream>>>(
      query, w_conv, w_q, b, w_k, qpb, wkT_hi);
  fused_attn_kernel<<<dim3(NB * NCHUNK), dim3(512), 0, stream>>>(
      key, gumbel, v, qpb, wkT_hi, part, out_align);
  combine_kernel<<<dim3(NB * 8), dim3(256), 0, stream>>>(part, out_ctx, out_align);
}